// Round 15
// baseline (36.915 us; speedup 1.0000x reference)
//
#include <hip/hip_runtime.h>
#include <hip/hip_cooperative_groups.h>

#define Bn 8
#define Hn 128
#define Wn 128
#define Cn 64
#define Dn 16
#define NS 26                 // 5*5 neighbors + self
#define NPX (Bn * Hn * Wn)    // 131072 pixels

#define KPW 132
#define KP_IMG (KPW * KPW)    // 17424 uint4
#define NBORD 66560           // 64 images x 1040 border cells

#define WS_Q_OFF_B   16384
#define WS_KP_OFF_B  (WS_Q_OFF_B + 8 * NPX * 16)
#define WS_NEEDED    ((size_t)WS_KP_OFF_B + (size_t)64 * KP_IMG * 16)

typedef _Float16 h2    __attribute__((ext_vector_type(2)));
typedef _Float16 f16x8 __attribute__((ext_vector_type(8)));
typedef float    f32x4 __attribute__((ext_vector_type(4)));

__device__ __forceinline__ unsigned int pkf16(float a, float b) {
    return __builtin_bit_cast(unsigned int, __builtin_amdgcn_cvt_pkrtz(a, b));
}
__device__ __forceinline__ float f16lo(unsigned int u) {
    return (float)__builtin_bit_cast(_Float16, (unsigned short)(u & 0xffffu));
}
__device__ __forceinline__ float f16hi(unsigned int u) {
    return (float)__builtin_bit_cast(_Float16, (unsigned short)(u >> 16));
}
__device__ __forceinline__ float dot2(unsigned int a, unsigned int b, float c) {
    return __builtin_amdgcn_fdot2(__builtin_bit_cast(h2, a),
                                  __builtin_bit_cast(h2, b), c, false);
}
__device__ __forceinline__ f16x8 pk8(float4 a, float4 b) {
    const uint4 u = make_uint4(pkf16(a.x, a.y), pkf16(a.z, a.w),
                               pkf16(b.x, b.y), pkf16(b.z, b.w));
    return __builtin_bit_cast(f16x8, u);
}
__device__ __forceinline__ void pack_w_entry(const float* W, int e, uint4* dst) {
    const int h  = e >> 7;
    const int kt = (e >> 6) & 1;
    const int l  = e & 63;
    const int dd = l & 15;
    const int cb = kt * 32 + ((l >> 4) << 3);
    const float* base = W + h * (Cn * Dn) + dd;
    uint4 v;
    v.x = pkf16(base[(cb + 0) * Dn], base[(cb + 1) * Dn]);
    v.y = pkf16(base[(cb + 2) * Dn], base[(cb + 3) * Dn]);
    v.z = pkf16(base[(cb + 4) * Dn], base[(cb + 5) * Dn]);
    v.w = pkf16(base[(cb + 6) * Dn], base[(cb + 7) * Dn]);
    *dst = v;
}

// ======== single cooperative kernel: proj-k phase, grid sync, attn phase ====
__global__ __launch_bounds__(256, 4)
void fused_all(const float* __restrict__ mainp, const float* __restrict__ refp,
               const float* __restrict__ Wm, const float* __restrict__ Wr,
               uint2* __restrict__ kp2, uint4* __restrict__ kp4,
               uint4* __restrict__ wfm, float* __restrict__ out)
{
    __shared__ __align__(16) unsigned int sU[3328];   // 13312 B, time-shared

    const int tid  = threadIdx.x;
    const int blk  = blockIdx.x;          // [0,1024)
    const int lane = tid & 63;
    const int wv   = tid >> 6;
    const int px16 = lane & 15;
    const int lg   = lane >> 4;

    // ---------------- phase 1: k projection (128 px / block) ----------------
    if (blk < 2) {                         // Wm fragments -> global
        const int idx = blk * 256 + tid;   // covers 512
        pack_w_entry(Wm, idx, &wfm[idx]);
    }
    if (tid < 65) {                        // border zeroing: 1024*65 = 66560
        const int idx = blk * 65 + tid;
        const int pb = idx / 1040;
        const int r  = idx - pb * 1040;
        int row, col;
        if (r < 528) { const int q = r / 132; row = (q < 2) ? q : 128 + q; col = r - q * 132; }
        else { const int r2 = r - 528; const int s = r2 & 3; row = 2 + (r2 >> 2); col = (s < 2) ? s : 128 + s; }
        kp4[(size_t)pb * KP_IMG + row * KPW + col] = make_uint4(0, 0, 0, 0);
    }
    uint4* sW = (uint4*)sU;                // Wr pack (8 KB of sU)
    for (int e = tid; e < 512; e += 256) pack_w_entry(Wr, e, &sW[e]);

    const int sw1   = ((blk & 7) << 7) | (blk >> 3);   // batch = blk&7 -> XCD
    const int wbase = sw1 * 128 + wv * 32;
    float4 raw[8];
#pragma unroll
    for (int g = 0; g < 2; ++g) {
        const float* rrow = refp + (size_t)(wbase + g * 16 + px16) * Cn + lg * 8;
        raw[g * 4 + 0] = *(const float4*)(rrow);
        raw[g * 4 + 1] = *(const float4*)(rrow + 4);
        raw[g * 4 + 2] = *(const float4*)(rrow + 32);
        raw[g * 4 + 3] = *(const float4*)(rrow + 36);
    }
    __syncthreads();

    {
        f16x8 br[4][2];
#pragma unroll
        for (int h = 0; h < 4; ++h)
#pragma unroll
            for (int t = 0; t < 2; ++t)
                br[h][t] = __builtin_bit_cast(f16x8, sW[(h * 2 + t) * 64 + lane]);
        const int halfsel  = lg >> 1;
        const int wordpair = lg & 1;
#pragma unroll
        for (int g = 0; g < 2; ++g) {
            const f16x8 Ar0 = pk8(raw[g * 4 + 0], raw[g * 4 + 1]);
            const f16x8 Ar1 = pk8(raw[g * 4 + 2], raw[g * 4 + 3]);
            const int px = wbase + g * 16 + px16;
            const int bb = px >> 14;
            const int yy = (px & 16383) >> 7;
            const int xx = px & 127;
            const int o  = (yy + 2) * KPW + (xx + 2);
#pragma unroll
            for (int h = 0; h < 4; ++h) {
                f32x4 z = {0.f, 0.f, 0.f, 0.f};
                z = __builtin_amdgcn_mfma_f32_16x16x32_f16(br[h][0], Ar0, z, 0, 0, 0);
                z = __builtin_amdgcn_mfma_f32_16x16x32_f16(br[h][1], Ar1, z, 0, 0, 0);
                const int w = h * 2 + halfsel;
                kp2[((size_t)(w * 8 + bb) * KP_IMG + o) * 2 + wordpair] =
                    make_uint2(pkf16(z[0], z[1]), pkf16(z[2], z[3]));
            }
        }
    }

    // prefetch tile-0 main fragments (k-independent) BEFORE the grid sync
    const int b     = blk & 7;
    const int tile0 = b * 256 + (blk >> 3) * 2;
    float4 m0, m1, m2, m3;
    {
        const int y  = (tile0 >> 1) & 127;
        const int x0 = (tile0 & 1) * 64;
        const float* mrow = mainp +
            (size_t)((b * Hn + y) * Wn + x0 + wv * 16 + px16) * Cn + lg * 8;
        m0 = *(const float4*)(mrow);
        m1 = *(const float4*)(mrow + 4);
        m2 = *(const float4*)(mrow + 32);
        m3 = *(const float4*)(mrow + 36);
    }

    cooperative_groups::this_grid().sync();

    // ---------------- phase 2: attention (2 row-tiles / block) --------------
    f16x8 bm[4][2];
#pragma unroll
    for (int h = 0; h < 4; ++h)
#pragma unroll
        for (int t = 0; t < 2; ++t)
            bm[h][t] = __builtin_bit_cast(f16x8, wfm[(h * 2 + t) * 64 + lane]);

    const int head = __builtin_amdgcn_readfirstlane(wv);

    for (int t = 0; t < 2; ++t) {
        const int tile = tile0 + t;
        const int y  = (tile >> 1) & 127;
        const int x0 = (tile & 1) * 64;
        if (t == 1) {
            __syncthreads();   // prior tile's sP reads complete before sQ reuse
            const float* mrow = mainp +
                (size_t)((b * Hn + y) * Wn + x0 + wv * 16 + px16) * Cn + lg * 8;
            m0 = *(const float4*)(mrow);
            m1 = *(const float4*)(mrow + 4);
            m2 = *(const float4*)(mrow + 32);
            m3 = *(const float4*)(mrow + 36);
        }
        const f16x8 Am0 = pk8(m0, m1), Am1 = pk8(m2, m3);
#pragma unroll
        for (int h = 0; h < 4; ++h) {
            f32x4 z = {0.f, 0.f, 0.f, 0.f};
            z = __builtin_amdgcn_mfma_f32_16x16x32_f16(bm[h][0], Am0, z, 0, 0, 0);
            z = __builtin_amdgcn_mfma_f32_16x16x32_f16(bm[h][1], Am1, z, 0, 0, 0);
            *(uint2*)&sU[(h * 64 + wv * 16 + px16) * 8 + lg * 2] =
                make_uint2(pkf16(z[0], z[1]), pkf16(z[2], z[3]));
        }
        __syncthreads();   // sQ ready

        const uint4 qa = *(const uint4*)&sU[(head * 64 + lane) * 8];
        const uint4 qb = *(const uint4*)&sU[(head * 64 + lane) * 8 + 4];
        const uint4* klo = kp4 + ((size_t)(head * 2 + 0) * 8 + b) * KP_IMG;
        const uint4* khi = kp4 + ((size_t)(head * 2 + 1) * 8 + b) * KP_IMG;

        float sc[NS];
#pragma unroll
        for (int di = 0; di < 5; ++di) {
            const int p0 = (y + di) * KPW + x0 + lane;
            uint4 kl[5], kh[5];
#pragma unroll
            for (int dj = 0; dj < 5; ++dj) { kl[dj] = klo[p0 + dj]; kh[dj] = khi[p0 + dj]; }
#pragma unroll
            for (int dj = 0; dj < 5; ++dj) {
                float s0 = dot2(qa.x, kl[dj].x, 0.f);
                float s1 = dot2(qb.x, kh[dj].x, 0.f);
                s0 = dot2(qa.y, kl[dj].y, s0);
                s1 = dot2(qb.y, kh[dj].y, s1);
                s0 = dot2(qa.z, kl[dj].z, s0);
                s1 = dot2(qb.z, kh[dj].z, s1);
                s0 = dot2(qa.w, kl[dj].w, s0);
                s1 = dot2(qb.w, kh[dj].w, s1);
                sc[di * 5 + dj] = s0 + s1;
            }
        }
        {
            float s0 = dot2(qa.x, qa.x, 0.f);
            float s1 = dot2(qb.x, qb.x, 0.f);
            s0 = dot2(qa.y, qa.y, s0);
            s1 = dot2(qb.y, qb.y, s1);
            s0 = dot2(qa.z, qa.z, s0);
            s1 = dot2(qb.z, qb.z, s1);
            s0 = dot2(qa.w, qa.w, s0);
            s1 = dot2(qb.w, qb.w, s1);
            sc[25] = s0 + s1;
        }

        float mx = sc[0];
#pragma unroll
        for (int i = 1; i < NS; ++i) mx = fmaxf(mx, sc[i]);
        float ssum = 0.f;
#pragma unroll
        for (int i = 0; i < NS; ++i) { sc[i] = __expf(sc[i] - mx); ssum += sc[i]; }
        const float inv = 1.0f / ssum;
#pragma unroll
        for (int i = 0; i < NS; ++i) sc[i] *= inv;

        __syncthreads();   // sQ reads done; buffer becomes sP
        {
            unsigned int* myrow = sU + (wv * 64 + lane) * 13;
#pragma unroll
            for (int j = 0; j < 13; ++j) myrow[j] = pkf16(sc[2 * j], sc[2 * j + 1]);
        }
        __syncthreads();

        const size_t ob = ((size_t)(b * Hn + y) * Wn + x0) * NS;
        for (int idx = tid; idx < 64 * 13; idx += 256) {
            const int px = idx / 13;
            const int p  = idx - px * 13;
            const unsigned int u0 = sU[(0 * 64 + px) * 13 + p];
            const unsigned int u1 = sU[(1 * 64 + px) * 13 + p];
            const unsigned int u2 = sU[(2 * 64 + px) * 13 + p];
            const unsigned int u3 = sU[(3 * 64 + px) * 13 + p];
            const float lo = f16lo(u0) + f16lo(u1) + f16lo(u2) + f16lo(u3);
            const float hi = f16hi(u0) + f16hi(u1) + f16hi(u2) + f16hi(u3);
            *(float2*)(out + ob + (size_t)px * NS + 2 * p) =
                make_float2(lo * 0.25f, hi * 0.25f);
        }
    }
}

// ======== fallback A: R14 two-kernel path (same ws layout) ========
__global__ __launch_bounds__(256, 2)
void proj_k(const float* __restrict__ refp,
            const float* __restrict__ Wr,
            const float* __restrict__ Wm,
            uint2* __restrict__ kp2,
            uint4* __restrict__ kp4,
            uint4* __restrict__ wfm)
{
    __shared__ uint4 sW[512];
    const int tid = threadIdx.x;
    const int wg  = blockIdx.x;                    // 512 blocks
    const int sw  = ((wg & 7) << 6) | (wg >> 3);
    {
        const int idx = wg * 256 + tid;
        if (idx < 512) pack_w_entry(Wm, idx, &wfm[idx]);
    }
    if (tid < 130) {
        const int idx = wg * 130 + tid;
        const int pb = idx / 1040;
        const int r  = idx - pb * 1040;
        int row, col;
        if (r < 528) { const int q = r / 132; row = (q < 2) ? q : 128 + q; col = r - q * 132; }
        else { const int r2 = r - 528; const int s = r2 & 3; row = 2 + (r2 >> 2); col = (s < 2) ? s : 128 + s; }
        kp4[(size_t)pb * KP_IMG + row * KPW + col] = make_uint4(0, 0, 0, 0);
    }
    for (int e = tid; e < 512; e += 256) pack_w_entry(Wr, e, &sW[e]);

    const int lane = tid & 63;
    const int wv   = tid >> 6;
    const int px16 = lane & 15;
    const int lg   = lane >> 4;
    const int wbase = sw * 256 + wv * 64;
    float4 raw[16];
#pragma unroll
    for (int g = 0; g < 4; ++g) {
        const float* rrow = refp + (size_t)(wbase + g * 16 + px16) * Cn + lg * 8;
        raw[g * 4 + 0] = *(const float4*)(rrow);
        raw[g * 4 + 1] = *(const float4*)(rrow + 4);
        raw[g * 4 + 2] = *(const float4*)(rrow + 32);
        raw[g * 4 + 3] = *(const float4*)(rrow + 36);
    }
    __syncthreads();
    f16x8 br[4][2];
#pragma unroll
    for (int h = 0; h < 4; ++h)
#pragma unroll
        for (int t = 0; t < 2; ++t)
            br[h][t] = __builtin_bit_cast(f16x8, sW[(h * 2 + t) * 64 + lane]);
    const int halfsel  = lg >> 1;
    const int wordpair = lg & 1;
#pragma unroll
    for (int g = 0; g < 4; ++g) {
        const f16x8 Ar0 = pk8(raw[g * 4 + 0], raw[g * 4 + 1]);
        const f16x8 Ar1 = pk8(raw[g * 4 + 2], raw[g * 4 + 3]);
        const int px = wbase + g * 16 + px16;
        const int bb = px >> 14;
        const int yy = (px & 16383) >> 7;
        const int xx = px & 127;
        const int o  = (yy + 2) * KPW + (xx + 2);
#pragma unroll
        for (int h = 0; h < 4; ++h) {
            f32x4 z = {0.f, 0.f, 0.f, 0.f};
            z = __builtin_amdgcn_mfma_f32_16x16x32_f16(br[h][0], Ar0, z, 0, 0, 0);
            z = __builtin_amdgcn_mfma_f32_16x16x32_f16(br[h][1], Ar1, z, 0, 0, 0);
            const int w = h * 2 + halfsel;
            kp2[((size_t)(w * 8 + bb) * KP_IMG + o) * 2 + wordpair] =
                make_uint2(pkf16(z[0], z[1]), pkf16(z[2], z[3]));
        }
    }
}

__global__ __launch_bounds__(256, 4)
void attn_row_fq(const float* __restrict__ mainp,
                 const uint4* __restrict__ wfm,
                 const uint4* __restrict__ kp,
                 float* __restrict__ out)
{
    __shared__ __align__(16) unsigned int sU[3328];
    const int tid  = threadIdx.x;
    const int lane = tid & 63;
    const int wv   = tid >> 6;
    const int wg = blockIdx.x;
    const int sw = ((wg & 7) << 8) | (wg >> 3);
    const int b  = sw >> 8;
    const int y  = (sw >> 1) & 127;
    const int x0 = (sw & 1) * 64;
    const int px16 = lane & 15;
    const int lg   = lane >> 4;
    const float* mrow = mainp +
        (size_t)((b * Hn + y) * Wn + x0 + wv * 16 + px16) * Cn + lg * 8;
    const float4 m0 = *(const float4*)(mrow);
    const float4 m1 = *(const float4*)(mrow + 4);
    const float4 m2 = *(const float4*)(mrow + 32);
    const float4 m3 = *(const float4*)(mrow + 36);
    f16x8 bm[4][2];
#pragma unroll
    for (int h = 0; h < 4; ++h)
#pragma unroll
        for (int t = 0; t < 2; ++t)
            bm[h][t] = __builtin_bit_cast(f16x8, wfm[(h * 2 + t) * 64 + lane]);
    const f16x8 Am0 = pk8(m0, m1), Am1 = pk8(m2, m3);
#pragma unroll
    for (int h = 0; h < 4; ++h) {
        f32x4 z = {0.f, 0.f, 0.f, 0.f};
        z = __builtin_amdgcn_mfma_f32_16x16x32_f16(bm[h][0], Am0, z, 0, 0, 0);
        z = __builtin_amdgcn_mfma_f32_16x16x32_f16(bm[h][1], Am1, z, 0, 0, 0);
        *(uint2*)&sU[(h * 64 + wv * 16 + px16) * 8 + lg * 2] =
            make_uint2(pkf16(z[0], z[1]), pkf16(z[2], z[3]));
    }
    __syncthreads();
    const int head = __builtin_amdgcn_readfirstlane(wv);
    const uint4 qa = *(const uint4*)&sU[(head * 64 + lane) * 8];
    const uint4 qb = *(const uint4*)&sU[(head * 64 + lane) * 8 + 4];
    const uint4* klo = kp + ((head * 2 + 0) * 8 + b) * KP_IMG;
    const uint4* khi = kp + ((head * 2 + 1) * 8 + b) * KP_IMG;
    float sc[NS];
#pragma unroll
    for (int di = 0; di < 5; ++di) {
        const int p0 = (y + di) * KPW + x0 + lane;
        uint4 kl[5], kh[5];
#pragma unroll
        for (int dj = 0; dj < 5; ++dj) { kl[dj] = klo[p0 + dj]; kh[dj] = khi[p0 + dj]; }
#pragma unroll
        for (int dj = 0; dj < 5; ++dj) {
            float s0 = dot2(qa.x, kl[dj].x, 0.f);
            float s1 = dot2(qb.x, kh[dj].x, 0.f);
            s0 = dot2(qa.y, kl[dj].y, s0);
            s1 = dot2(qb.y, kh[dj].y, s1);
            s0 = dot2(qa.z, kl[dj].z, s0);
            s1 = dot2(qb.z, kh[dj].z, s1);
            s0 = dot2(qa.w, kl[dj].w, s0);
            s1 = dot2(qb.w, kh[dj].w, s1);
            sc[di * 5 + dj] = s0 + s1;
        }
    }
    {
        float s0 = dot2(qa.x, qa.x, 0.f);
        float s1 = dot2(qb.x, qb.x, 0.f);
        s0 = dot2(qa.y, qa.y, s0);
        s1 = dot2(qb.y, qb.y, s1);
        s0 = dot2(qa.z, qa.z, s0);
        s1 = dot2(qb.z, qb.z, s1);
        s0 = dot2(qa.w, qa.w, s0);
        s1 = dot2(qb.w, qb.w, s1);
        sc[25] = s0 + s1;
    }
    float mx = sc[0];
#pragma unroll
    for (int i = 1; i < NS; ++i) mx = fmaxf(mx, sc[i]);
    float ssum = 0.f;
#pragma unroll
    for (int i = 0; i < NS; ++i) { sc[i] = __expf(sc[i] - mx); ssum += sc[i]; }
    const float inv = 1.0f / ssum;
#pragma unroll
    for (int i = 0; i < NS; ++i) sc[i] *= inv;
    __syncthreads();
    {
        unsigned int* myrow = sU + (wv * 64 + lane) * 13;
#pragma unroll
        for (int j = 0; j < 13; ++j) myrow[j] = pkf16(sc[2 * j], sc[2 * j + 1]);
    }
    __syncthreads();
    const size_t ob = ((size_t)(b * Hn + y) * Wn + x0) * NS;
    for (int idx = tid; idx < 64 * 13; idx += 256) {
        const int px = idx / 13;
        const int p  = idx - px * 13;
        const unsigned int u0 = sU[(0 * 64 + px) * 13 + p];
        const unsigned int u1 = sU[(1 * 64 + px) * 13 + p];
        const unsigned int u2 = sU[(2 * 64 + px) * 13 + p];
        const unsigned int u3 = sU[(3 * 64 + px) * 13 + p];
        const float lo = f16lo(u0) + f16lo(u1) + f16lo(u2) + f16lo(u3);
        const float hi = f16hi(u0) + f16hi(u1) + f16hi(u2) + f16hi(u3);
        *(float2*)(out + ob + (size_t)px * NS + 2 * p) =
            make_float2(lo * 0.25f, hi * 0.25f);
    }
}

// ======== fallback B (tiny ws): R4 monolithic ========
#define TILE 8
#define HALO 12
#define NHALO (HALO * HALO)
#define PXW 36
__global__ void pack_weights(const float* __restrict__ Wm,
                             const float* __restrict__ Wr,
                             unsigned int* __restrict__ wp) {
    const int idx = blockIdx.x * 256 + threadIdx.x;
    if (idx < 2 * 4 * 32 * Dn) {
        const int t = idx >> 11;
        const int r = idx & 2047;
        const int h = r >> 9;
        const int m = (r >> 4) & 31;
        const int d = r & 15;
        const float* W = t ? Wr : Wm;
        wp[idx] = pkf16(W[h * (Cn * Dn) + (2 * m) * Dn + d],
                        W[h * (Cn * Dn) + (2 * m + 1) * Dn + d]);
    }
}
__global__ __launch_bounds__(256, 4)
void local_attn_fused_r4(const float* __restrict__ mainp,
                         const float* __restrict__ refp,
                         const unsigned int* __restrict__ wp,
                         float* __restrict__ out)
{
    __shared__ unsigned int sK[NHALO * PXW];
    const int tid  = threadIdx.x;
    const int lane = tid & 63;
    const int wv   = tid >> 6;
    const int head = __builtin_amdgcn_readfirstlane(wv);
    const int b    = blockIdx.z;
    const int y0   = blockIdx.y * TILE;
    const int x0   = blockIdx.x * TILE;
    const unsigned int* wmh = wp + head * (32 * Dn);
    const unsigned int* wrh = wp + 2048 + head * (32 * Dn);
    for (int p = lane; p < NHALO; p += 64) {
        const int hr = p / HALO;
        const int hc = p - hr * HALO;
        const int gy = y0 - 2 + hr;
        const int gx = x0 - 2 + hc;
        float acc[Dn];
#pragma unroll
        for (int d = 0; d < Dn; ++d) acc[d] = 0.f;
        if ((unsigned)gy < (unsigned)Hn && (unsigned)gx < (unsigned)Wn) {
            const float4* rp4 = (const float4*)(refp + (((size_t)b * Hn + gy) * Wn + gx) * Cn);
#pragma unroll
            for (int c4 = 0; c4 < Cn / 4; ++c4) {
                const float4 rv = rp4[c4];
                const unsigned int r01 = pkf16(rv.x, rv.y);
                const unsigned int r23 = pkf16(rv.z, rv.w);
                const unsigned int* w0 = wrh + (2 * c4) * Dn;
                const unsigned int* w1 = wrh + (2 * c4 + 1) * Dn;
#pragma unroll
                for (int d = 0; d < Dn; ++d) acc[d] = dot2(r01, w0[d], acc[d]);
#pragma unroll
                for (int d = 0; d < Dn; ++d) acc[d] = dot2(r23, w1[d], acc[d]);
            }
        }
        unsigned int pk[8];
#pragma unroll
        for (int j = 0; j < 8; ++j) pk[j] = pkf16(acc[2 * j], acc[2 * j + 1]);
        unsigned int* dst = sK + p * PXW + head * 8;
        *(uint4*)(dst)     = make_uint4(pk[0], pk[1], pk[2], pk[3]);
        *(uint4*)(dst + 4) = make_uint4(pk[4], pk[5], pk[6], pk[7]);
    }
    const int pr = lane >> 3;
    const int pc = lane & 7;
    const float4* mp4 = (const float4*)(mainp + (((size_t)b * Hn + (y0 + pr)) * Wn + (x0 + pc)) * Cn);
    float q[Dn];
#pragma unroll
    for (int d = 0; d < Dn; ++d) q[d] = 0.f;
#pragma unroll
    for (int c4 = 0; c4 < Cn / 4; ++c4) {
        const float4 mv = mp4[c4];
        const unsigned int m01 = pkf16(mv.x, mv.y);
        const unsigned int m23 = pkf16(mv.z, mv.w);
        const unsigned int* w0 = wmh + (2 * c4) * Dn;
        const unsigned int* w1 = wmh + (2 * c4 + 1) * Dn;
#pragma unroll
        for (int d = 0; d < Dn; ++d) q[d] = dot2(m01, w0[d], q[d]);
#pragma unroll
        for (int d = 0; d < Dn; ++d) q[d] = dot2(m23, w1[d], q[d]);
    }
    unsigned int qh[8];
#pragma unroll
    for (int j = 0; j < 8; ++j) qh[j] = pkf16(q[2 * j], q[2 * j + 1]);
    __syncthreads();
    float sc[NS];
#pragma unroll
    for (int di = 0; di < 5; ++di) {
#pragma unroll
        for (int dj = 0; dj < 5; ++dj) {
            const int h = (pr + di) * HALO + (pc + dj);
            const unsigned int* src = sK + h * PXW + head * 8;
            const uint4 ka = *(const uint4*)(src);
            const uint4 kb = *(const uint4*)(src + 4);
            float s;
            s = dot2(qh[0], ka.x, 0.f);
            s = dot2(qh[1], ka.y, s);
            s = dot2(qh[2], ka.z, s);
            s = dot2(qh[3], ka.w, s);
            s = dot2(qh[4], kb.x, s);
            s = dot2(qh[5], kb.y, s);
            s = dot2(qh[6], kb.z, s);
            s = dot2(qh[7], kb.w, s);
            sc[di * 5 + dj] = s;
        }
    }
    {
        float s = q[0] * q[0];
#pragma unroll
        for (int d = 1; d < Dn; ++d) s = fmaf(q[d], q[d], s);
        sc[25] = s;
    }
    float mx = sc[0];
#pragma unroll
    for (int i = 1; i < NS; ++i) mx = fmaxf(mx, sc[i]);
    float ssum = 0.f;
#pragma unroll
    for (int i = 0; i < NS; ++i) { sc[i] = __expf(sc[i] - mx); ssum += sc[i]; }
    const float inv = 1.0f / ssum;
#pragma unroll
    for (int i = 0; i < NS; ++i) sc[i] *= inv;
    __syncthreads();
    {
        unsigned int* myrow = sK + (wv * 64 + lane) * 14;
#pragma unroll
        for (int j = 0; j < 13; ++j) myrow[j] = pkf16(sc[2 * j], sc[2 * j + 1]);
    }
    __syncthreads();
    const unsigned short* sA = (const unsigned short*)sK;
    const size_t obase = (((size_t)b * Hn + y0) * Wn + x0) * NS;
    for (int idx = tid; idx < TILE * TILE * NS; idx += 256) {
        const int r   = idx / (TILE * NS);
        const int t   = idx - r * (TILE * NS);
        const int c   = t / NS;
        const int i   = t - c * NS;
        const int ppx = r * TILE + c;
        float acc = 0.f;
#pragma unroll
        for (int h = 0; h < 4; ++h)
            acc += (float)__builtin_bit_cast(_Float16, sA[(h * 64 + ppx) * 28 + i]);
        out[obase + (size_t)r * (Wn * NS) + t] = 0.25f * acc;
    }
}

extern "C" void kernel_launch(void* const* d_in, const int* in_sizes, int n_in,
                              void* d_out, int out_size, void* d_ws, size_t ws_size,
                              hipStream_t stream) {
    (void)in_sizes; (void)n_in; (void)out_size;
    const float* mainp = (const float*)d_in[0];
    const float* refp  = (const float*)d_in[1];
    const float* Wm    = (const float*)d_in[2];
    const float* Wr    = (const float*)d_in[3];
    float* out = (float*)d_out;

    if (ws_size >= WS_NEEDED) {
        uint4* wfm = (uint4*)d_ws;
        uint4* kpb = (uint4*)((char*)d_ws + WS_KP_OFF_B);
        uint2* kp2 = (uint2*)kpb;

        int maxb = 0;
        (void)hipOccupancyMaxActiveBlocksPerMultiprocessor(&maxb, fused_all, 256, 0);
        if (maxb >= 4) {
            void* args[] = {(void*)&mainp, (void*)&refp, (void*)&Wm, (void*)&Wr,
                            (void*)&kp2, (void*)&kpb, (void*)&wfm, (void*)&out};
            hipLaunchCooperativeKernel((const void*)fused_all, dim3(1024), dim3(256),
                                       args, 0, stream);
        } else {
            proj_k<<<512, 256, 0, stream>>>(refp, Wr, Wm, kp2, kpb, wfm);
            attn_row_fq<<<2048, 256, 0, stream>>>(mainp, wfm, kpb, out);
        }
    } else {
        unsigned int* wpk = (unsigned int*)d_ws;
        pack_weights<<<16, 256, 0, stream>>>(Wm, Wr, wpk);
        dim3 grid2(Wn / TILE, Hn / TILE, Bn);
        local_attn_fused_r4<<<grid2, 256, 0, stream>>>(mainp, refp, wpk, out);
    }
}

// Round 16
// 35.994 us; speedup vs baseline: 1.0256x; 1.0256x over previous
//
#include <hip/hip_runtime.h>

#define Bn 8
#define Hn 128
#define Wn 128
#define Cn 64
#define Dn 16
#define NS 26                 // 5*5 neighbors + self
#define NPX (Bn * Hn * Wn)    // 131072 pixels

// padded k geometry: per (plane,b) a 132x132 uint4 image (2-px zero border)
#define KPW 132
#define KP_IMG (KPW * KPW)    // 17424 uint4
#define NBORD 66560           // 64 images x 1040 border cells

// ws layout: [0,16KB) spare | [unused q region] | kpad uint4[8][8][KP_IMG]
#define WS_Q_OFF_B   16384
#define WS_KP_OFF_B  (WS_Q_OFF_B + 8 * NPX * 16)
#define WS_NEEDED    ((size_t)WS_KP_OFF_B + (size_t)64 * KP_IMG * 16)

typedef _Float16 h2    __attribute__((ext_vector_type(2)));
typedef _Float16 f16x8 __attribute__((ext_vector_type(8)));
typedef float    f32x4 __attribute__((ext_vector_type(4)));

__device__ __forceinline__ unsigned int pkf16(float a, float b) {
    return __builtin_bit_cast(unsigned int, __builtin_amdgcn_cvt_pkrtz(a, b));
}
__device__ __forceinline__ float dot2(unsigned int a, unsigned int b, float c) {
    return __builtin_amdgcn_fdot2(__builtin_bit_cast(h2, a),
                                  __builtin_bit_cast(h2, b), c, false);
}
__device__ __forceinline__ f16x8 pk8(float4 a, float4 b) {
    const uint4 u = make_uint4(pkf16(a.x, a.y), pkf16(a.z, a.w),
                               pkf16(b.x, b.y), pkf16(b.z, b.w));
    return __builtin_bit_cast(f16x8, u);
}

// ---- pass 1: k-only projection (border-zero + Wr LDS pack + MFMA) ----
// Swapped-operand MFMA: D[d][px], col=px=lane&15 -> direct packed uint2
// stores. Batch->XCD chunked swizzle matches attn so k stays in the
// producing XCD's L2.
__global__ __launch_bounds__(256, 3)
void proj_k(const float* __restrict__ refp,
            const float* __restrict__ Wr,
            uint2* __restrict__ kp2,
            uint4* __restrict__ kp4)
{
    __shared__ uint4 sW[512];   // 8 KB fragment-ordered f16 ref-weights

    const int tid = threadIdx.x;
    const int wg  = blockIdx.x;
    const int sw  = ((wg & 7) << 8) | (wg >> 3);   // bijective; batch -> XCD

    // distributed border zeroing (consumed only by the later attn kernel)
    {
        const int idx = wg * 33 + tid;
        if (tid < 33 && idx < NBORD) {
            const int pb = idx / 1040;
            const int r  = idx - pb * 1040;
            int row, col;
            if (r < 528) { const int q = r / 132; row = (q < 2) ? q : 128 + q; col = r - q * 132; }
            else { const int r2 = r - 528; const int s = r2 & 3; row = 2 + (r2 >> 2); col = (s < 2) ? s : 128 + s; }
            kp4[(size_t)pb * KP_IMG + row * KPW + col] = make_uint4(0, 0, 0, 0);
        }
    }

    // cooperative Wr pack: entry e = h*128 + kt*64 + l
    for (int e = tid; e < 512; e += 256) {
        const int h  = e >> 7;
        const int kt = (e >> 6) & 1;
        const int l  = e & 63;
        const int dd = l & 15;
        const int cb = kt * 32 + ((l >> 4) << 3);
        const float* base = Wr + h * (Cn * Dn) + dd;
        uint4 v;
        v.x = pkf16(base[(cb + 0) * Dn], base[(cb + 1) * Dn]);
        v.y = pkf16(base[(cb + 2) * Dn], base[(cb + 3) * Dn]);
        v.z = pkf16(base[(cb + 4) * Dn], base[(cb + 5) * Dn]);
        v.w = pkf16(base[(cb + 6) * Dn], base[(cb + 7) * Dn]);
        sW[e] = v;
    }

    // ref fragment loads (pre-barrier: HBM latency overlaps the pack)
    const int lane = tid & 63;
    const int wv   = tid >> 6;
    const int gbase = sw * 64 + wv * 16;
    const int px16 = lane & 15;
    const int lg   = lane >> 4;

    const float* rrow = refp + (size_t)(gbase + px16) * Cn + lg * 8;
    const float4 r0 = *(const float4*)(rrow);
    const float4 r1 = *(const float4*)(rrow + 4);
    const float4 r2 = *(const float4*)(rrow + 32);
    const float4 r3 = *(const float4*)(rrow + 36);

    __syncthreads();

    f16x8 br[4][2];
#pragma unroll
    for (int h = 0; h < 4; ++h)
#pragma unroll
        for (int t = 0; t < 2; ++t)
            br[h][t] = __builtin_bit_cast(f16x8, sW[(h * 2 + t) * 64 + lane]);

    const f16x8 Ar0 = pk8(r0, r1), Ar1 = pk8(r2, r3);

    const int px = gbase + px16;
    const int bb = px >> 14;
    const int yy = (px & 16383) >> 7;
    const int xx = px & 127;
    const int o  = (yy + 2) * KPW + (xx + 2);
    const int halfsel  = lg >> 1;
    const int wordpair = lg & 1;

#pragma unroll
    for (int h = 0; h < 4; ++h) {
        f32x4 z = {0.f, 0.f, 0.f, 0.f};
        z = __builtin_amdgcn_mfma_f32_16x16x32_f16(br[h][0], Ar0, z, 0, 0, 0);
        z = __builtin_amdgcn_mfma_f32_16x16x32_f16(br[h][1], Ar1, z, 0, 0, 0);
        const int w = h * 2 + halfsel;
        kp2[((size_t)(w * 8 + bb) * KP_IMG + o) * 2 + wordpair] =
            make_uint2(pkf16(z[0], z[1]), pkf16(z[2], z[3]));
    }
}

// ---- pass 2: fused q-projection + scores. Wave wv builds q for its own
// 16-px group x all heads (MFMA), LDS-exchanges to per-lane full-q, then
// wave = head for the score loop. LDS 21.5 KB:
// region A = Wm-pack (8K) UNION combine buffer (13.3K); region B = sQ 8K.
__global__ __launch_bounds__(256, 3)
void attn_row_fq(const float* __restrict__ mainp,
                 const float* __restrict__ Wm,
                 const uint4* __restrict__ kp,
                 float* __restrict__ out)
{
    __shared__ __align__(16) unsigned int sA_[3328];   // sW(2048w) U sP(3328w)
    __shared__ __align__(16) unsigned int sQ[4 * 64 * 8];   // 8192 B

    const int tid  = threadIdx.x;
    const int lane = tid & 63;
    const int wv   = tid >> 6;
    const int wg = blockIdx.x;
    const int sw = ((wg & 7) << 8) | (wg >> 3);
    const int b  = sw >> 8;
    const int y  = (sw >> 1) & 127;
    const int x0 = (sw & 1) * 64;

    // ---- cooperative Wm pack into region A ----
    uint4* sW = (uint4*)sA_;
    for (int e = tid; e < 512; e += 256) {
        const int h  = e >> 7;
        const int kt = (e >> 6) & 1;
        const int l  = e & 63;
        const int dd = l & 15;
        const int cb = kt * 32 + ((l >> 4) << 3);
        const float* base = Wm + h * (Cn * Dn) + dd;
        uint4 v;
        v.x = pkf16(base[(cb + 0) * Dn], base[(cb + 1) * Dn]);
        v.y = pkf16(base[(cb + 2) * Dn], base[(cb + 3) * Dn]);
        v.z = pkf16(base[(cb + 4) * Dn], base[(cb + 5) * Dn]);
        v.w = pkf16(base[(cb + 6) * Dn], base[(cb + 7) * Dn]);
        sW[e] = v;
    }

    // main B-frag loads for my px-group (pre-barrier)
    const int px16 = lane & 15;
    const int lg   = lane >> 4;
    const float* mrow = mainp +
        (size_t)((b * Hn + y) * Wn + x0 + wv * 16 + px16) * Cn + lg * 8;
    const float4 m0 = *(const float4*)(mrow);
    const float4 m1 = *(const float4*)(mrow + 4);
    const float4 m2 = *(const float4*)(mrow + 32);
    const float4 m3 = *(const float4*)(mrow + 36);

    __syncthreads();   // sW ready

    f16x8 bm[4][2];
#pragma unroll
    for (int h = 0; h < 4; ++h)
#pragma unroll
        for (int t = 0; t < 2; ++t)
            bm[h][t] = __builtin_bit_cast(f16x8, sW[(h * 2 + t) * 64 + lane]);

    const f16x8 Am0 = pk8(m0, m1), Am1 = pk8(m2, m3);
    const int rr = lg;   // output d-row group
#pragma unroll
    for (int h = 0; h < 4; ++h) {
        f32x4 z = {0.f, 0.f, 0.f, 0.f};
        z = __builtin_amdgcn_mfma_f32_16x16x32_f16(bm[h][0], Am0, z, 0, 0, 0);
        z = __builtin_amdgcn_mfma_f32_16x16x32_f16(bm[h][1], Am1, z, 0, 0, 0);
        *(uint2*)&sQ[(h * 64 + wv * 16 + px16) * 8 + rr * 2] =
            make_uint2(pkf16(z[0], z[1]), pkf16(z[2], z[3]));
    }

    __syncthreads();   // sQ ready; sW dead from here on

    const int head = __builtin_amdgcn_readfirstlane(wv);
    const uint4 qa = *(const uint4*)&sQ[(head * 64 + lane) * 8];
    const uint4 qb = *(const uint4*)&sQ[(head * 64 + lane) * 8 + 4];

    const uint4* klo = kp + ((head * 2 + 0) * 8 + b) * KP_IMG;
    const uint4* khi = kp + ((head * 2 + 1) * 8 + b) * KP_IMG;

    float sc[NS];
#pragma unroll
    for (int di = 0; di < 5; ++di) {
        const int p0 = (y + di) * KPW + x0 + lane;   // padded row y+di-2, col x-2
        uint4 kl[5], kh[5];
#pragma unroll
        for (int dj = 0; dj < 5; ++dj) { kl[dj] = klo[p0 + dj]; kh[dj] = khi[p0 + dj]; }
#pragma unroll
        for (int dj = 0; dj < 5; ++dj) {
            float s0 = dot2(qa.x, kl[dj].x, 0.f);
            float s1 = dot2(qb.x, kh[dj].x, 0.f);
            s0 = dot2(qa.y, kl[dj].y, s0);
            s1 = dot2(qb.y, kh[dj].y, s1);
            s0 = dot2(qa.z, kl[dj].z, s0);
            s1 = dot2(qb.z, kh[dj].z, s1);
            s0 = dot2(qa.w, kl[dj].w, s0);
            s1 = dot2(qb.w, kh[dj].w, s1);
            sc[di * 5 + dj] = s0 + s1;
        }
    }
    {   // self score q.q
        float s0 = dot2(qa.x, qa.x, 0.f);
        float s1 = dot2(qb.x, qb.x, 0.f);
        s0 = dot2(qa.y, qa.y, s0);
        s1 = dot2(qb.y, qb.y, s1);
        s0 = dot2(qa.z, qa.z, s0);
        s1 = dot2(qb.z, qb.z, s1);
        s0 = dot2(qa.w, qa.w, s0);
        s1 = dot2(qb.w, qb.w, s1);
        sc[25] = s0 + s1;
    }

    // softmax
    float mx = sc[0];
#pragma unroll
    for (int i = 1; i < NS; ++i) mx = fmaxf(mx, sc[i]);
    float ssum = 0.f;
#pragma unroll
    for (int i = 0; i < NS; ++i) { sc[i] = __expf(sc[i] - mx); ssum += sc[i]; }
    const float inv = 1.0f / ssum;
#pragma unroll
    for (int i = 0; i < NS; ++i) sc[i] *= inv;

    // u16 fixed-point attn -> region A (sW is dead: every wave passed bar 2)
    unsigned int* sP = sA_;
    {
        unsigned int* myrow = sP + (wv * 64 + lane) * 13;
#pragma unroll
        for (int j = 0; j < 13; ++j) {
            const unsigned int ulo = (unsigned int)(sc[2 * j] * 65535.f + 0.5f);
            const unsigned int uhi = (unsigned int)(sc[2 * j + 1] * 65535.f + 0.5f);
            myrow[j] = ulo | (uhi << 16);
        }
    }
    __syncthreads();

    // head-mean + store: 64 px x 26 floats = 1664 contiguous floats
    const size_t ob = ((size_t)(b * Hn + y) * Wn + x0) * NS;
    for (int idx = tid; idx < 64 * 13; idx += 256) {
        const int px = idx / 13;
        const int p  = idx - px * 13;
        const unsigned int u0 = sP[(0 * 64 + px) * 13 + p];
        const unsigned int u1 = sP[(1 * 64 + px) * 13 + p];
        const unsigned int u2 = sP[(2 * 64 + px) * 13 + p];
        const unsigned int u3 = sP[(3 * 64 + px) * 13 + p];
        const float lo = (float)((u0 & 0xffffu) + (u1 & 0xffffu) +
                                 (u2 & 0xffffu) + (u3 & 0xffffu));
        const float hi = (float)((u0 >> 16) + (u1 >> 16) + (u2 >> 16) + (u3 >> 16));
        const float k = 1.f / (4.f * 65535.f);
        *(float2*)(out + ob + (size_t)px * NS + 2 * p) = make_float2(lo * k, hi * k);
    }
}

// ================= fallback path (small ws): R4 monolithic ==========
#define TILE 8
#define HALO 12
#define NHALO (HALO * HALO)
#define PXW 36
__global__ void pack_weights(const float* __restrict__ Wm,
                             const float* __restrict__ Wr,
                             unsigned int* __restrict__ wp) {
    const int idx = blockIdx.x * 256 + threadIdx.x;
    if (idx < 2 * 4 * 32 * Dn) {
        const int t = idx >> 11;
        const int r = idx & 2047;
        const int h = r >> 9;
        const int m = (r >> 4) & 31;
        const int d = r & 15;
        const float* W = t ? Wr : Wm;
        wp[idx] = pkf16(W[h * (Cn * Dn) + (2 * m) * Dn + d],
                        W[h * (Cn * Dn) + (2 * m + 1) * Dn + d]);
    }
}
__global__ __launch_bounds__(256, 4)
void local_attn_fused_r4(const float* __restrict__ mainp,
                         const float* __restrict__ refp,
                         const unsigned int* __restrict__ wp,
                         float* __restrict__ out)
{
    __shared__ unsigned int sK[NHALO * PXW];
    const int tid  = threadIdx.x;
    const int lane = tid & 63;
    const int wv   = tid >> 6;
    const int head = __builtin_amdgcn_readfirstlane(wv);
    const int b    = blockIdx.z;
    const int y0   = blockIdx.y * TILE;
    const int x0   = blockIdx.x * TILE;
    const unsigned int* wmh = wp + head * (32 * Dn);
    const unsigned int* wrh = wp + 2048 + head * (32 * Dn);
    for (int p = lane; p < NHALO; p += 64) {
        const int hr = p / HALO;
        const int hc = p - hr * HALO;
        const int gy = y0 - 2 + hr;
        const int gx = x0 - 2 + hc;
        float acc[Dn];
#pragma unroll
        for (int d = 0; d < Dn; ++d) acc[d] = 0.f;
        if ((unsigned)gy < (unsigned)Hn && (unsigned)gx < (unsigned)Wn) {
            const float4* rp4 = (const float4*)(refp + (((size_t)b * Hn + gy) * Wn + gx) * Cn);
#pragma unroll
            for (int c4 = 0; c4 < Cn / 4; ++c4) {
                const float4 rv = rp4[c4];
                const unsigned int r01 = pkf16(rv.x, rv.y);
                const unsigned int r23 = pkf16(rv.z, rv.w);
                const unsigned int* w0 = wrh + (2 * c4) * Dn;
                const unsigned int* w1 = wrh + (2 * c4 + 1) * Dn;
#pragma unroll
                for (int d = 0; d < Dn; ++d) acc[d] = dot2(r01, w0[d], acc[d]);
#pragma unroll
                for (int d = 0; d < Dn; ++d) acc[d] = dot2(r23, w1[d], acc[d]);
            }
        }
        unsigned int pk[8];
#pragma unroll
        for (int j = 0; j < 8; ++j) pk[j] = pkf16(acc[2 * j], acc[2 * j + 1]);
        unsigned int* dst = sK + p * PXW + head * 8;
        *(uint4*)(dst)     = make_uint4(pk[0], pk[1], pk[2], pk[3]);
        *(uint4*)(dst + 4) = make_uint4(pk[4], pk[5], pk[6], pk[7]);
    }
    const int pr = lane >> 3;
    const int pc = lane & 7;
    const float4* mp4 = (const float4*)(mainp + (((size_t)b * Hn + (y0 + pr)) * Wn + (x0 + pc)) * Cn);
    float q[Dn];
#pragma unroll
    for (int d = 0; d < Dn; ++d) q[d] = 0.f;
#pragma unroll
    for (int c4 = 0; c4 < Cn / 4; ++c4) {
        const float4 mv = mp4[c4];
        const unsigned int m01 = pkf16(mv.x, mv.y);
        const unsigned int m23 = pkf16(mv.z, mv.w);
        const unsigned int* w0 = wmh + (2 * c4) * Dn;
        const unsigned int* w1 = wmh + (2 * c4 + 1) * Dn;
#pragma unroll
        for (int d = 0; d < Dn; ++d) q[d] = dot2(m01, w0[d], q[d]);
#pragma unroll
        for (int d = 0; d < Dn; ++d) q[d] = dot2(m23, w1[d], q[d]);
    }
    unsigned int qh[8];
#pragma unroll
    for (int j = 0; j < 8; ++j) qh[j] = pkf16(q[2 * j], q[2 * j + 1]);
    __syncthreads();
    float sc[NS];
#pragma unroll
    for (int di = 0; di < 5; ++di) {
#pragma unroll
        for (int dj = 0; dj < 5; ++dj) {
            const int h = (pr + di) * HALO + (pc + dj);
            const unsigned int* src = sK + h * PXW + head * 8;
            const uint4 ka = *(const uint4*)(src);
            const uint4 kb = *(const uint4*)(src + 4);
            float s;
            s = dot2(qh[0], ka.x, 0.f);
            s = dot2(qh[1], ka.y, s);
            s = dot2(qh[2], ka.z, s);
            s = dot2(qh[3], ka.w, s);
            s = dot2(qh[4], kb.x, s);
            s = dot2(qh[5], kb.y, s);
            s = dot2(qh[6], kb.z, s);
            s = dot2(qh[7], kb.w, s);
            sc[di * 5 + dj] = s;
        }
    }
    {
        float s = q[0] * q[0];
#pragma unroll
        for (int d = 1; d < Dn; ++d) s = fmaf(q[d], q[d], s);
        sc[25] = s;
    }
    float mx = sc[0];
#pragma unroll
    for (int i = 1; i < NS; ++i) mx = fmaxf(mx, sc[i]);
    float ssum = 0.f;
#pragma unroll
    for (int i = 0; i < NS; ++i) { sc[i] = __expf(sc[i] - mx); ssum += sc[i]; }
    const float inv = 1.0f / ssum;
#pragma unroll
    for (int i = 0; i < NS; ++i) sc[i] *= inv;
    __syncthreads();
    {
        unsigned int* myrow = sK + (wv * 64 + lane) * 14;
#pragma unroll
        for (int j = 0; j < 13; ++j) myrow[j] = pkf16(sc[2 * j], sc[2 * j + 1]);
    }
    __syncthreads();
    const unsigned short* sA = (const unsigned short*)sK;
    const size_t obase = (((size_t)b * Hn + y0) * Wn + x0) * NS;
    for (int idx = tid; idx < TILE * TILE * NS; idx += 256) {
        const int r   = idx / (TILE * NS);
        const int t   = idx - r * (TILE * NS);
        const int c   = t / NS;
        const int i   = t - c * NS;
        const int ppx = r * TILE + c;
        float acc = 0.f;
#pragma unroll
        for (int h = 0; h < 4; ++h)
            acc += (float)__builtin_bit_cast(_Float16, sA[(h * 64 + ppx) * 28 + i]);
        out[obase + (size_t)r * (Wn * NS) + t] = 0.25f * acc;
    }
}

extern "C" void kernel_launch(void* const* d_in, const int* in_sizes, int n_in,
                              void* d_out, int out_size, void* d_ws, size_t ws_size,
                              hipStream_t stream) {
    (void)in_sizes; (void)n_in; (void)out_size;
    const float* mainp = (const float*)d_in[0];
    const float* refp  = (const float*)d_in[1];
    const float* Wm    = (const float*)d_in[2];
    const float* Wr    = (const float*)d_in[3];
    float* out = (float*)d_out;

    if (ws_size >= WS_NEEDED) {
        uint4* kpb = (uint4*)((char*)d_ws + WS_KP_OFF_B);
        proj_k<<<2048, 256, 0, stream>>>(refp, Wr, (uint2*)kpb, kpb);
        attn_row_fq<<<2048, 256, 0, stream>>>(mainp, Wm, kpb, out);
    } else {
        unsigned int* wpk = (unsigned int*)d_ws;
        pack_weights<<<16, 256, 0, stream>>>(Wm, Wr, wpk);
        dim3 grid2(Wn / TILE, Hn / TILE, Bn);
        local_attn_fused_r4<<<grid2, 256, 0, stream>>>(mainp, refp, wpk, out);
    }
}